// Round 1
// baseline (119.155 us; speedup 1.0000x reference)
//
#include <hip/hip_runtime.h>
#include <math.h>

#define NSPL 128
#define SCALE 512.0f

// One block = 16x16 pixel sub-tile (inside one 64x64 mask tile).
// Threads 0..127 stage spline constants + compute tile mask; ballot-compacted
// active list (ascending index order -> deterministic, matches ref sum order).
__global__ __launch_bounds__(256) void spline_render(
    const float* __restrict__ ga, const float* __restrict__ gb,
    const float* __restrict__ gc, const float* __restrict__ glw,
    const float* __restrict__ glc, float* __restrict__ out)
{
    __shared__ float s_ay[NSPL], s_ax[NSPL];
    __shared__ float s_Ay[NSPL], s_Ax[NSPL];
    __shared__ float s_By[NSPL], s_Bx[NSPL];
    __shared__ float s_ca[NSPL], s_ca3[NSPL], s_ax2[NSPL];
    __shared__ float s_cbK[NSPL], s_nB[NSPL];
    __shared__ float s_lw[NSPL], s_lc[NSPL];
    __shared__ int   s_act[NSPL];
    __shared__ int   s_wc[2];

    const int t  = threadIdx.x;
    const int bx = blockIdx.x & 31;   // 512/16 = 32 blocks across
    const int by = blockIdx.x >> 5;
    const int tile_y0 = (by >> 2) << 6;  // 64x64 mask-tile base of this block
    const int tile_x0 = (bx >> 2) << 6;

    bool flag = false;
    if (t < NSPL) {
        const int n = t;
        const float ay  = ga[2*n],  ax  = ga[2*n+1];
        const float by_ = gb[2*n],  bx_ = gb[2*n+1];
        const float cy  = gc[2*n],  cx  = gc[2*n+1];
        const float w   = glw[n];

        // ---- bbox/tile mask (reference _bbox_mask, fp32) ----
        float miy = fminf(ay, cy), may = fmaxf(ay, cy);
        float mix = fminf(ax, cx), maxx = fmaxf(ax, cx);
        bool cond = (by_ < miy) || (by_ > may) || (bx_ < mix) || (bx_ > maxx);
        float dny = ay - 2.0f*by_ + cy;
        float dnx = ax - 2.0f*bx_ + cx;
        bool dok = (fabsf(dny) > 1e-9f) && (fabsf(dnx) > 1e-9f);
        float tty = fminf(fmaxf((ay - by_) / ((fabsf(dny) > 1e-9f) ? dny : 1e-9f), 0.0f), 1.0f);
        float ttx = fminf(fmaxf((ax - bx_) / ((fabsf(dnx) > 1e-9f) ? dnx : 1e-9f), 0.0f), 1.0f);
        float sy = 1.0f - tty, sx = 1.0f - ttx;
        float qqy = sy*sy*ay + 2.0f*sy*tty*by_ + tty*tty*cy;
        float qqx = sx*sx*ax + 2.0f*sx*ttx*bx_ + ttx*ttx*cx;
        if (cond && dok) {
            miy = fminf(miy, qqy); may = fmaxf(may, qqy);
            mix = fminf(mix, qqx); maxx = fmaxf(maxx, qqx);
        }
        float mg = floorf(3.0f * w);   // MARGIN = 0
        float mi_py = fminf(fmaxf(floorf(miy*SCALE) - mg, 0.0f), 512.0f);
        float ma_py = fminf(fmaxf(ceilf (may*SCALE) + mg, 0.0f), 512.0f);
        float mi_px = fminf(fmaxf(floorf(mix*SCALE) - mg, 0.0f), 512.0f);
        float ma_px = fminf(fmaxf(ceilf (maxx*SCALE) + mg, 0.0f), 512.0f);
        flag = (ma_py > (float)tile_y0) && (mi_py < (float)(tile_y0 + 64))
            && (ma_px > (float)tile_x0) && (mi_px < (float)(tile_x0 + 64));

        // ---- per-spline forward constants (reference _forward, fp32) ----
        float bby = by_ + 1e-5f, bbx = bx_ + 1e-5f;
        float Ay = bby - ay, Ax = bbx - ax;
        float By = cy - bby - Ay, Bx = cx - bbx - Ax;
        float BdB = By*By + Bx*Bx;
        float nB  = -BdB;                       // divide by -BdB, as reference
        float AdB = Ay*By + Ax*Bx;
        float ca  = (-3.0f * AdB) / nB;
        s_ay[n] = ay;  s_ax[n] = ax;
        s_Ay[n] = Ay;  s_Ax[n] = Ax;
        s_By[n] = By;  s_Bx[n] = Bx;
        s_ca[n] = ca;  s_ca3[n] = ca / 3.0f;  s_ax2[n] = ca * ca;
        s_cbK[n] = 2.0f * (Ay*Ay + Ax*Ax);
        s_nB[n] = nB;
        s_lw[n] = w;   s_lc[n] = glc[n];
    }

    // ---- deterministic compaction (2 waves cover 128 splines) ----
    unsigned long long bal = __ballot(flag);
    const int lane = t & 63;
    const int wid  = t >> 6;
    if (wid < 2 && lane == 0) s_wc[wid] = __popcll(bal);
    const int pre = __popcll(bal & ((1ull << lane) - 1ull));
    __syncthreads();
    if (flag) {
        int pos = (wid == 1 ? s_wc[0] : 0) + pre;
        s_act[pos] = t;
    }
    __syncthreads();
    const int nact = s_wc[0] + s_wc[1];

    // ---- per-pixel evaluation over active splines ----
    const int px_i = (bx << 4) + (t & 15);
    const int py_i = (by << 4) + (t >> 4);
    const float py = (float)py_i * (1.0f / 511.0f);
    const float px = (float)px_i * (1.0f / 511.0f);

    float sum = 0.0f;
    for (int i = 0; i < nact; ++i) {
        const int n = s_act[i];
        const float Ay = s_Ay[n], Ax = s_Ax[n];
        const float By = s_By[n], Bx = s_Bx[n];
        const float nB = s_nB[n];
        const float Cy = py - s_ay[n], Cx = px - s_ax[n];
        const float CdB = Cy*By + Cx*Bx;
        const float CdA = Cy*Ay + Cx*Ax;
        const float cb = (CdB - s_cbK[n]) / nB;
        const float cc = CdA / nB;
        const float ca = s_ca[n], ca3 = s_ca3[n], ax2 = s_ax2[n];

        // _solve_cubic (both branches, as reference computes both)
        const float p_  = cb - ax2 / 3.0f;
        const float p3  = p_ * p_ * p_;
        const float q   = ca * (2.0f*ax2 - 9.0f*cb) / 27.0f + cc;
        const float d   = q*q + 4.0f*p3 / 27.0f;
        const float sd  = sqrtf(fmaxf(d, 0.0f));
        const float root0 = cbrtf((sd - q) * 0.5f) + cbrtf((-sd - q) * 0.5f) - ca3;
        const float p3s = (fabsf(p3) > 1e-9f) ? p3 : 1e-9f;
        const float aarg = -sqrtf(fmaxf(-27.0f / p3s, 0.0f)) * q * 0.5f;
        const float v = acosf(fminf(fmaxf(aarg, -1.0f), 1.0f)) / 3.0f;
        const float m = cosf(v);
        const float nn = sinf(v) * 1.7320508075688772f;
        const float sp = sqrtf(fmaxf(-p_ / 3.0f, 0.0f));
        const float root1 = (m + m) * sp - ca3;
        const float root2 = (-nn - m) * sp - ca3;

        float T0 = (d > 0.0f) ? root0 : root1;
        float T1 = (d > 0.0f) ? root0 : root2;
        T0 = fminf(fmaxf(T0, 0.0f), 1.0f);
        T1 = fminf(fmaxf(T1, 0.0f), 1.0f);

        const float Dy = Ay + Ay, Dx = Ax + Ax;
        const float d1y = (Dy + By*T0)*T0 - Cy, d1x = (Dx + Bx*T0)*T0 - Cx;
        const float d2y = (Dy + By*T1)*T1 - Cy, d2x = (Dx + Bx*T1)*T1 - Cx;
        const float q1 = d1y*d1y + d1x*d1x;
        const float q2 = d2y*d2y + d2x*d2x;
        const float dist = sqrtf(fminf(q1, q2));

        const float w = s_lw[n];
        const float sarg = (w - dist) / w * 6.0f;
        sum += s_lc[n] / (1.0f + expf(-sarg));
    }

    out[py_i * 512 + px_i] = 1.0f - sum;
}

extern "C" void kernel_launch(void* const* d_in, const int* in_sizes, int n_in,
                              void* d_out, int out_size, void* d_ws, size_t ws_size,
                              hipStream_t stream) {
    const float* a  = (const float*)d_in[0];
    const float* b  = (const float*)d_in[1];
    const float* c  = (const float*)d_in[2];
    const float* lw = (const float*)d_in[3];
    const float* lc = (const float*)d_in[4];
    float* out = (float*)d_out;
    spline_render<<<dim3(1024), dim3(256), 0, stream>>>(a, b, c, lw, lc, out);
}

// Round 4
// 87.912 us; speedup vs baseline: 1.3554x; 1.3554x over previous
//
#include <hip/hip_runtime.h>
#include <math.h>

#define NSPL 128
#define SCALE 512.0f

// One block = 8x16 pixel sub-tile (8x8 per wave, inside one 64x64 mask tile).
// Numerics are byte-for-byte round-1 (known absmax 0.0439): libm transcendentals,
// true divides, default contraction. Speed comes only from value-identical
// structure: ballot branch-skip + packed LDS + square wave footprint.
__global__ __launch_bounds__(128) void spline_render(
    const float* __restrict__ ga, const float* __restrict__ gb,
    const float* __restrict__ gc, const float* __restrict__ glw,
    const float* __restrict__ glc, float* __restrict__ out)
{
    __shared__ float4 s_f0[NSPL], s_f1[NSPL], s_f2[NSPL];
    __shared__ float  s_lc[NSPL];
    __shared__ int    s_act[NSPL];
    __shared__ int    s_wc[2];

    const int t  = threadIdx.x;
    const int bx = blockIdx.x & 63;   // 64 blocks across (8 px each)
    const int by = blockIdx.x >> 6;   // 32 blocks down (16 px each)
    const int tile_y0 = (by >> 2) << 6;
    const int tile_x0 = (bx >> 3) << 6;

    bool flag = false;
    {
        // ---- round-1 mask + constants, verbatim ----
        const int n = t;
        const float ay  = ga[2*n],  ax  = ga[2*n+1];
        const float by_ = gb[2*n],  bx_ = gb[2*n+1];
        const float cy  = gc[2*n],  cx  = gc[2*n+1];
        const float w   = glw[n];

        float miy = fminf(ay, cy), may = fmaxf(ay, cy);
        float mix = fminf(ax, cx), maxx = fmaxf(ax, cx);
        bool cond = (by_ < miy) || (by_ > may) || (bx_ < mix) || (bx_ > maxx);
        float dny = ay - 2.0f*by_ + cy;
        float dnx = ax - 2.0f*bx_ + cx;
        bool dok = (fabsf(dny) > 1e-9f) && (fabsf(dnx) > 1e-9f);
        float tty = fminf(fmaxf((ay - by_) / ((fabsf(dny) > 1e-9f) ? dny : 1e-9f), 0.0f), 1.0f);
        float ttx = fminf(fmaxf((ax - bx_) / ((fabsf(dnx) > 1e-9f) ? dnx : 1e-9f), 0.0f), 1.0f);
        float sy = 1.0f - tty, sx = 1.0f - ttx;
        float qqy = sy*sy*ay + 2.0f*sy*tty*by_ + tty*tty*cy;
        float qqx = sx*sx*ax + 2.0f*sx*ttx*bx_ + ttx*ttx*cx;
        if (cond && dok) {
            miy = fminf(miy, qqy); may = fmaxf(may, qqy);
            mix = fminf(mix, qqx); maxx = fmaxf(maxx, qqx);
        }
        float mg = floorf(3.0f * w);   // MARGIN = 0
        float mi_py = fminf(fmaxf(floorf(miy*SCALE) - mg, 0.0f), 512.0f);
        float ma_py = fminf(fmaxf(ceilf (may*SCALE) + mg, 0.0f), 512.0f);
        float mi_px = fminf(fmaxf(floorf(mix*SCALE) - mg, 0.0f), 512.0f);
        float ma_px = fminf(fmaxf(ceilf (maxx*SCALE) + mg, 0.0f), 512.0f);
        flag = (ma_py > (float)tile_y0) && (mi_py < (float)(tile_y0 + 64))
            && (ma_px > (float)tile_x0) && (mi_px < (float)(tile_x0 + 64));

        float bby = by_ + 1e-5f, bbx = bx_ + 1e-5f;
        float Ay = bby - ay, Ax = bbx - ax;
        float By = cy - bby - Ay, Bx = cx - bbx - Ax;
        float BdB = By*By + Bx*Bx;
        float nB  = -BdB;
        float AdB = Ay*By + Ax*Bx;
        float ca  = (-3.0f * AdB) / nB;
        s_f0[n] = make_float4(ay, ax, Ay, Ax);
        s_f1[n] = make_float4(By, Bx, ca, ca / 3.0f);
        s_f2[n] = make_float4(ca * ca, 2.0f * (Ay*Ay + Ax*Ax), nB, w);
        s_lc[n] = glc[n];
    }

    // ---- deterministic compaction (2 waves over 128 splines) ----
    unsigned long long bal = __ballot(flag);
    const int lane = t & 63;
    const int wid  = t >> 6;
    if (lane == 0) s_wc[wid] = __popcll(bal);
    const int pre = __popcll(bal & ((1ull << lane) - 1ull));
    __syncthreads();
    if (flag) {
        int pos = (wid == 1 ? s_wc[0] : 0) + pre;
        s_act[pos] = t;
    }
    __syncthreads();
    const int nact = s_wc[0] + s_wc[1];

    // ---- per-pixel evaluation (round-1 grid coords) ----
    const int px_i = (bx << 3) + (t & 7);
    const int py_i = (by << 4) + (t >> 3);
    const float py = (float)py_i * (1.0f / 511.0f);
    const float px = (float)px_i * (1.0f / 511.0f);

    float sum = 0.0f;
    for (int i = 0; i < nact; ++i) {
        const int n = s_act[i];
        const float4 f0 = s_f0[n];
        const float4 f1 = s_f1[n];
        const float4 f2 = s_f2[n];
        const float Ay = f0.z, Ax = f0.w;
        const float By = f1.x, Bx = f1.y;
        const float ca = f1.z, ca3 = f1.w;
        const float ax2 = f2.x, cbK = f2.y, nB = f2.z, w = f2.w;

        // ---- round-1 expressions, verbatim ----
        const float Cy = py - f0.x, Cx = px - f0.y;
        const float CdB = Cy*By + Cx*Bx;
        const float CdA = Cy*Ay + Cx*Ax;
        const float cb = (CdB - cbK) / nB;
        const float cc = CdA / nB;

        const float p_  = cb - ax2 / 3.0f;
        const float p3  = p_ * p_ * p_;
        const float q   = ca * (2.0f*ax2 - 9.0f*cb) / 27.0f + cc;
        const float d   = q*q + 4.0f*p3 / 27.0f;

        const bool sgl = d > 0.0f;
        const unsigned long long bd = __ballot(sgl);
        float T0 = 0.0f, T1 = 0.0f;
        if (bd) {  // some lane takes the single-root branch
            const float sd = sqrtf(fmaxf(d, 0.0f));
            const float r0 = cbrtf((sd - q) * 0.5f) + cbrtf((-sd - q) * 0.5f) - ca3;
            T0 = r0; T1 = r0;
        }
        if (bd != ~0ull) {  // some lane takes the trig branch
            const float p3s = (fabsf(p3) > 1e-9f) ? p3 : 1e-9f;
            const float aarg = -sqrtf(fmaxf(-27.0f / p3s, 0.0f)) * q * 0.5f;
            const float v = acosf(fminf(fmaxf(aarg, -1.0f), 1.0f)) / 3.0f;
            const float m = cosf(v);
            const float nn = sinf(v) * 1.7320508075688772f;
            const float sp = sqrtf(fmaxf(-p_ / 3.0f, 0.0f));
            const float r1 = (m + m) * sp - ca3;
            const float r2 = (-nn - m) * sp - ca3;
            if (!sgl) { T0 = r1; T1 = r2; }
        }
        T0 = fminf(fmaxf(T0, 0.0f), 1.0f);
        T1 = fminf(fmaxf(T1, 0.0f), 1.0f);

        const float Dy = Ay + Ay, Dx = Ax + Ax;
        const float d1y = (Dy + By*T0)*T0 - Cy, d1x = (Dx + Bx*T0)*T0 - Cx;
        const float d2y = (Dy + By*T1)*T1 - Cy, d2x = (Dx + Bx*T1)*T1 - Cx;
        const float q1 = d1y*d1y + d1x*d1x;
        const float q2 = d2y*d2y + d2x*d2x;
        const float dist = sqrtf(fminf(q1, q2));

        const float sarg = (w - dist) / w * 6.0f;
        sum += s_lc[n] / (1.0f + expf(-sarg));
    }

    out[py_i * 512 + px_i] = 1.0f - sum;
}

extern "C" void kernel_launch(void* const* d_in, const int* in_sizes, int n_in,
                              void* d_out, int out_size, void* d_ws, size_t ws_size,
                              hipStream_t stream) {
    const float* a  = (const float*)d_in[0];
    const float* b  = (const float*)d_in[1];
    const float* c  = (const float*)d_in[2];
    const float* lw = (const float*)d_in[3];
    const float* lc = (const float*)d_in[4];
    float* out = (float*)d_out;
    spline_render<<<dim3(2048), dim3(128), 0, stream>>>(a, b, c, lw, lc, out);
}

// Round 5
// 80.147 us; speedup vs baseline: 1.4867x; 1.0969x over previous
//
#include <hip/hip_runtime.h>
#include <math.h>

#define NSPL 128
#define SCALE 512.0f

// ---------------- workspace layout (bytes) ----------------
// float4 cst0[128] @ 0      (ay, ax, Ay, Ax)
// float4 cst1[128] @ 2048   (By, Bx, ca, ca/3)
// float4 cst2[128] @ 4096   (ca^2, 2AdA, nB, w)
// float4 ebox[128] @ 6144   (emi_y, ema_y, emi_x, ema_x)  expanded px bounds
// float  lc  [128] @ 8192
// int    nact[64]  @ 8704
// int    act[64*128] @ 8960
// total 41728 B

// Stage: one block per 64x64 tile; thread t = spline t. Ref-exact mask ->
// compacted ascending active list per tile. Block 0 also writes the
// constant / expanded-bbox tables (same fp expressions as round 4).
__global__ __launch_bounds__(128) void stage_k(
    const float* __restrict__ ga, const float* __restrict__ gb,
    const float* __restrict__ gc, const float* __restrict__ glw,
    const float* __restrict__ glc,
    float4* __restrict__ cst0, float4* __restrict__ cst1,
    float4* __restrict__ cst2, float4* __restrict__ ebox,
    float* __restrict__ lcw, int* __restrict__ nact, int* __restrict__ act)
{
    __shared__ int s_wc[2];
    const int tile = blockIdx.x;          // r*8 + c
    const float ty0 = (float)((tile >> 3) << 6);
    const float tx0 = (float)((tile & 7) << 6);
    const int t = threadIdx.x;

    const int n = t;
    const float ay  = ga[2*n],  ax  = ga[2*n+1];
    const float by_ = gb[2*n],  bx_ = gb[2*n+1];
    const float cy  = gc[2*n],  cx  = gc[2*n+1];
    const float w   = glw[n];

    // ---- reference _bbox_mask, round-4 verbatim ----
    float miy = fminf(ay, cy), may = fmaxf(ay, cy);
    float mix = fminf(ax, cx), maxx = fmaxf(ax, cx);
    bool cond = (by_ < miy) || (by_ > may) || (bx_ < mix) || (bx_ > maxx);
    float dny = ay - 2.0f*by_ + cy;
    float dnx = ax - 2.0f*bx_ + cx;
    bool dok = (fabsf(dny) > 1e-9f) && (fabsf(dnx) > 1e-9f);
    float tty = fminf(fmaxf((ay - by_) / ((fabsf(dny) > 1e-9f) ? dny : 1e-9f), 0.0f), 1.0f);
    float ttx = fminf(fmaxf((ax - bx_) / ((fabsf(dnx) > 1e-9f) ? dnx : 1e-9f), 0.0f), 1.0f);
    float sy = 1.0f - tty, sx = 1.0f - ttx;
    float qqy = sy*sy*ay + 2.0f*sy*tty*by_ + tty*tty*cy;
    float qqx = sx*sx*ax + 2.0f*sx*ttx*bx_ + ttx*ttx*cx;
    if (cond && dok) {
        miy = fminf(miy, qqy); may = fmaxf(may, qqy);
        mix = fminf(mix, qqx); maxx = fmaxf(maxx, qqx);
    }
    float mg = floorf(3.0f * w);   // MARGIN = 0
    float mi_py = fminf(fmaxf(floorf(miy*SCALE) - mg, 0.0f), 512.0f);
    float ma_py = fminf(fmaxf(ceilf (may*SCALE) + mg, 0.0f), 512.0f);
    float mi_px = fminf(fmaxf(floorf(mix*SCALE) - mg, 0.0f), 512.0f);
    float ma_px = fminf(fmaxf(ceilf (maxx*SCALE) + mg, 0.0f), 512.0f);
    bool flag = (ma_py > ty0) && (mi_py < ty0 + 64.0f)
             && (ma_px > tx0) && (mi_px < tx0 + 64.0f);

    if (blockIdx.x == 0) {
        // per-spline constants (round-4 expressions)
        float bby = by_ + 1e-5f, bbx = bx_ + 1e-5f;
        float Ay = bby - ay, Ax = bbx - ax;
        float By = cy - bby - Ay, Bx = cx - bbx - Ax;
        float BdB = By*By + Bx*Bx;
        float nB  = -BdB;
        float AdB = Ay*By + Ax*Bx;
        float ca  = (-3.0f * AdB) / nB;
        cst0[n] = make_float4(ay, ax, Ay, Ax);
        cst1[n] = make_float4(By, Bx, ca, ca / 3.0f);
        cst2[n] = make_float4(ca * ca, 2.0f * (Ay*Ay + Ax*Ax), nB, w);
        lcw[n]  = glc[n];
        // expanded bbox: contributions beyond E px are < 1.2e-5 each
        float E = fmaf(2.9f * 512.0f, w, 3.0f);
        ebox[n] = make_float4(mi_py - E, ma_py + E, mi_px - E, ma_px + E);
    }

    // deterministic ascending compaction (2 waves)
    unsigned long long bal = __ballot(flag);
    const int lane = t & 63;
    const int wid  = t >> 6;
    if (lane == 0) s_wc[wid] = __popcll(bal);
    const int pre = __popcll(bal & ((1ull << lane) - 1ull));
    __syncthreads();
    if (flag) {
        int pos = (wid == 1 ? s_wc[0] : 0) + pre;
        act[tile * NSPL + pos] = t;
    }
    if (t == 0) nact[tile] = s_wc[0] + s_wc[1];
}

// Render: one 64-thread block = 8x8 pixels. Filter tile's active list by
// expanded bbox (order-preserving ballot compaction), then round-4-verbatim
// evaluation with uniform-branch skips.
__global__ __launch_bounds__(64) void render_k(
    const float4* __restrict__ cst0, const float4* __restrict__ cst1,
    const float4* __restrict__ cst2, const float4* __restrict__ ebox,
    const float* __restrict__ lcw, const int* __restrict__ nact,
    const int* __restrict__ act, float* __restrict__ out)
{
    __shared__ int s_list[NSPL];
    const int t   = threadIdx.x;
    const int rbx = blockIdx.x & 63;
    const int rby = blockIdx.x >> 6;
    const int tile = ((rby >> 3) << 3) | (rbx >> 3);
    const float ry0 = (float)(rby << 3), rx0 = (float)(rbx << 3);

    const int na = nact[tile];
    const int* __restrict__ al = act + tile * NSPL;

    int cnt = 0;
    for (int base = 0; base < na; base += 64) {
        const int j = base + t;
        bool keep = false; int n = 0;
        if (j < na) {
            n = al[j];
            const float4 eb = ebox[n];
            keep = (eb.y > ry0) && (eb.x < ry0 + 8.0f)
                && (eb.w > rx0) && (eb.z < rx0 + 8.0f);
        }
        const unsigned long long b = __ballot(keep);
        const int pos = cnt + __popcll(b & ((1ull << t) - 1ull));
        if (keep) s_list[pos] = n;
        cnt += __popcll(b);
    }
    __syncthreads();   // single wave: just orders LDS writes vs reads

    const int px_i = (rbx << 3) + (t & 7);
    const int py_i = (rby << 3) + (t >> 3);
    const float py = (float)py_i * (1.0f / 511.0f);
    const float px = (float)px_i * (1.0f / 511.0f);

    float sum = 0.0f;
    for (int i = 0; i < cnt; ++i) {
        const int n = __builtin_amdgcn_readfirstlane(s_list[i]);
        const float4 f0 = cst0[n];
        const float4 f1 = cst1[n];
        const float4 f2 = cst2[n];
        const float Ay = f0.z, Ax = f0.w;
        const float By = f1.x, Bx = f1.y;
        const float ca = f1.z, ca3 = f1.w;
        const float ax2 = f2.x, cbK = f2.y, nB = f2.z, w = f2.w;

        // ---- round-4 expressions, verbatim ----
        const float Cy = py - f0.x, Cx = px - f0.y;
        const float CdB = Cy*By + Cx*Bx;
        const float CdA = Cy*Ay + Cx*Ax;
        const float cb = (CdB - cbK) / nB;
        const float cc = CdA / nB;

        const float p_  = cb - ax2 / 3.0f;
        const float p3  = p_ * p_ * p_;
        const float q   = ca * (2.0f*ax2 - 9.0f*cb) / 27.0f + cc;
        const float d   = q*q + 4.0f*p3 / 27.0f;

        const bool sgl = d > 0.0f;
        const unsigned long long bd = __ballot(sgl);
        float T0 = 0.0f, T1 = 0.0f;
        if (bd) {
            const float sd = sqrtf(fmaxf(d, 0.0f));
            const float r0 = cbrtf((sd - q) * 0.5f) + cbrtf((-sd - q) * 0.5f) - ca3;
            T0 = r0; T1 = r0;
        }
        if (bd != ~0ull) {
            const float p3s = (fabsf(p3) > 1e-9f) ? p3 : 1e-9f;
            const float aarg = -sqrtf(fmaxf(-27.0f / p3s, 0.0f)) * q * 0.5f;
            const float v = acosf(fminf(fmaxf(aarg, -1.0f), 1.0f)) / 3.0f;
            const float m = cosf(v);
            const float nn = sinf(v) * 1.7320508075688772f;
            const float sp = sqrtf(fmaxf(-p_ / 3.0f, 0.0f));
            const float r1 = (m + m) * sp - ca3;
            const float r2 = (-nn - m) * sp - ca3;
            if (!sgl) { T0 = r1; T1 = r2; }
        }
        T0 = fminf(fmaxf(T0, 0.0f), 1.0f);
        T1 = fminf(fmaxf(T1, 0.0f), 1.0f);

        const float Dy = Ay + Ay, Dx = Ax + Ax;
        const float d1y = (Dy + By*T0)*T0 - Cy, d1x = (Dx + Bx*T0)*T0 - Cx;
        const float q1 = d1y*d1y + d1x*d1x;
        float dist;
        if (bd == ~0ull) {
            dist = sqrtf(q1);            // T1==T0 -> q2==q1 bitwise
        } else {
            const float d2y = (Dy + By*T1)*T1 - Cy, d2x = (Dx + Bx*T1)*T1 - Cx;
            const float q2 = d2y*d2y + d2x*d2x;
            dist = sqrtf(fminf(q1, q2));
        }

        const float sarg = (w - dist) / w * 6.0f;
        sum += lcw[n] / (1.0f + expf(-sarg));
    }

    out[py_i * 512 + px_i] = 1.0f - sum;
}

extern "C" void kernel_launch(void* const* d_in, const int* in_sizes, int n_in,
                              void* d_out, int out_size, void* d_ws, size_t ws_size,
                              hipStream_t stream) {
    const float* a  = (const float*)d_in[0];
    const float* b  = (const float*)d_in[1];
    const float* c  = (const float*)d_in[2];
    const float* lw = (const float*)d_in[3];
    const float* lc = (const float*)d_in[4];
    float* out = (float*)d_out;

    char* ws = (char*)d_ws;
    float4* cst0 = (float4*)(ws + 0);
    float4* cst1 = (float4*)(ws + 2048);
    float4* cst2 = (float4*)(ws + 4096);
    float4* ebox = (float4*)(ws + 6144);
    float*  lcw  = (float*)(ws + 8192);
    int*    nact = (int*)(ws + 8704);
    int*    act  = (int*)(ws + 8960);

    stage_k<<<dim3(64), dim3(128), 0, stream>>>(a, b, c, lw, lc,
                                                cst0, cst1, cst2, ebox, lcw, nact, act);
    render_k<<<dim3(4096), dim3(64), 0, stream>>>(cst0, cst1, cst2, ebox, lcw,
                                                  nact, act, out);
}

// Round 6
// 74.622 us; speedup vs baseline: 1.5968x; 1.0741x over previous
//
#include <hip/hip_runtime.h>
#include <math.h>

#define NSPL 128
#define SCALE 512.0f

// One block = 16x16 pixels (256 threads); each wave = one 8x8 quadrant.
// Phase 1 (threads 0..127): ref-exact 64x64-tile mask + per-spline constants
// + expanded bbox -> LDS. Phase 2: each wave ballot-filters the 128 splines
// against its 8x8 quadrant (ascending order preserved -> ref sum order), then
// evaluates with round-4-verbatim numerics (libm, true divides).
__global__ __launch_bounds__(256) void spline_render(
    const float* __restrict__ ga, const float* __restrict__ gb,
    const float* __restrict__ gc, const float* __restrict__ glw,
    const float* __restrict__ glc, float* __restrict__ out)
{
    __shared__ float4 s_f0[NSPL], s_f1[NSPL], s_f2[NSPL], s_eb[NSPL];
    __shared__ float  s_lc[NSPL];
    __shared__ int    s_wl[4][NSPL];

    const int t  = threadIdx.x;
    const int bx = blockIdx.x & 31;   // 32 blocks across (16 px each)
    const int by = blockIdx.x >> 5;   // 32 blocks down  (16 px each)
    const float ty0 = (float)((by >> 2) << 6);   // this block's 64x64 tile
    const float tx0 = (float)((bx >> 2) << 6);

    if (t < NSPL) {
        // ---- round-4 mask + constants, verbatim ----
        const int n = t;
        const float ay  = ga[2*n],  ax  = ga[2*n+1];
        const float by_ = gb[2*n],  bx_ = gb[2*n+1];
        const float cy  = gc[2*n],  cx  = gc[2*n+1];
        const float w   = glw[n];

        float miy = fminf(ay, cy), may = fmaxf(ay, cy);
        float mix = fminf(ax, cx), maxx = fmaxf(ax, cx);
        bool cond = (by_ < miy) || (by_ > may) || (bx_ < mix) || (bx_ > maxx);
        float dny = ay - 2.0f*by_ + cy;
        float dnx = ax - 2.0f*bx_ + cx;
        bool dok = (fabsf(dny) > 1e-9f) && (fabsf(dnx) > 1e-9f);
        float tty = fminf(fmaxf((ay - by_) / ((fabsf(dny) > 1e-9f) ? dny : 1e-9f), 0.0f), 1.0f);
        float ttx = fminf(fmaxf((ax - bx_) / ((fabsf(dnx) > 1e-9f) ? dnx : 1e-9f), 0.0f), 1.0f);
        float sy = 1.0f - tty, sx = 1.0f - ttx;
        float qqy = sy*sy*ay + 2.0f*sy*tty*by_ + tty*tty*cy;
        float qqx = sx*sx*ax + 2.0f*sx*ttx*bx_ + ttx*ttx*cx;
        if (cond && dok) {
            miy = fminf(miy, qqy); may = fmaxf(may, qqy);
            mix = fminf(mix, qqx); maxx = fmaxf(maxx, qqx);
        }
        float mg = floorf(3.0f * w);   // MARGIN = 0
        float mi_py = fminf(fmaxf(floorf(miy*SCALE) - mg, 0.0f), 512.0f);
        float ma_py = fminf(fmaxf(ceilf (may*SCALE) + mg, 0.0f), 512.0f);
        float mi_px = fminf(fmaxf(floorf(mix*SCALE) - mg, 0.0f), 512.0f);
        float ma_px = fminf(fmaxf(ceilf (maxx*SCALE) + mg, 0.0f), 512.0f);
        bool flag = (ma_py > ty0) && (mi_py < ty0 + 64.0f)
                 && (ma_px > tx0) && (mi_px < tx0 + 64.0f);

        float bby = by_ + 1e-5f, bbx = bx_ + 1e-5f;
        float Ay = bby - ay, Ax = bbx - ax;
        float By = cy - bby - Ay, Bx = cx - bbx - Ax;
        float BdB = By*By + Bx*Bx;
        float nB  = -BdB;
        float AdB = Ay*By + Ax*Bx;
        float ca  = (-3.0f * AdB) / nB;
        s_f0[n] = make_float4(ay, ax, Ay, Ax);
        s_f1[n] = make_float4(By, Bx, ca, ca / 3.0f);
        s_f2[n] = make_float4(ca * ca, 2.0f * (Ay*Ay + Ax*Ax), nB, w);
        s_lc[n] = glc[n];
        // expanded bbox: beyond E px each contribution < 1.2e-5 (round-5-proven)
        float E = fmaf(2.9f * 512.0f, w, 3.0f);
        s_eb[n] = flag ? make_float4(mi_py - E, ma_py + E, mi_px - E, ma_px + E)
                       : make_float4(1e30f, -1e30f, 1e30f, -1e30f);
    }
    __syncthreads();

    // ---- per-wave 8x8-quadrant filter (ascending, order-preserving) ----
    const int lane = t & 63;
    const int wv   = t >> 6;
    const int wx0 = (bx << 4) + ((wv & 1) << 3);
    const int wy0 = (by << 4) + ((wv >> 1) << 3);
    const float wy0f = (float)wy0, wx0f = (float)wx0;

    int cnt = 0;
    #pragma unroll
    for (int h = 0; h < 2; ++h) {
        const int n = (h << 6) + lane;
        const float4 eb = s_eb[n];
        const bool keep = (eb.y > wy0f) && (eb.x < wy0f + 8.0f)
                       && (eb.w > wx0f) && (eb.z < wx0f + 8.0f);
        const unsigned long long b = __ballot(keep);
        const int pos = cnt + __popcll(b & ((1ull << lane) - 1ull));
        if (keep) s_wl[wv][pos] = n;
        cnt += __popcll(b);
    }

    // ---- per-pixel evaluation ----
    const int px_i = wx0 + (lane & 7);
    const int py_i = wy0 + (lane >> 3);
    const float py = (float)py_i * (1.0f / 511.0f);
    const float px = (float)px_i * (1.0f / 511.0f);

    float sum = 0.0f;
    for (int i = 0; i < cnt; ++i) {
        const int n = s_wl[wv][i];
        const float4 f0 = s_f0[n];
        const float4 f1 = s_f1[n];
        const float4 f2 = s_f2[n];
        const float Ay = f0.z, Ax = f0.w;
        const float By = f1.x, Bx = f1.y;
        const float ca = f1.z, ca3 = f1.w;
        const float ax2 = f2.x, cbK = f2.y, nB = f2.z, w = f2.w;

        // ---- round-4 expressions, verbatim ----
        const float Cy = py - f0.x, Cx = px - f0.y;
        const float CdB = Cy*By + Cx*Bx;
        const float CdA = Cy*Ay + Cx*Ax;
        const float cb = (CdB - cbK) / nB;
        const float cc = CdA / nB;

        const float p_  = cb - ax2 / 3.0f;
        const float p3  = p_ * p_ * p_;
        const float q   = ca * (2.0f*ax2 - 9.0f*cb) / 27.0f + cc;
        const float d   = q*q + 4.0f*p3 / 27.0f;

        const bool sgl = d > 0.0f;
        const unsigned long long bd = __ballot(sgl);
        float T0 = 0.0f, T1 = 0.0f;
        if (bd) {  // some lane takes the single-root branch
            const float sd = sqrtf(fmaxf(d, 0.0f));
            const float r0 = cbrtf((sd - q) * 0.5f) + cbrtf((-sd - q) * 0.5f) - ca3;
            T0 = r0; T1 = r0;
        }
        if (bd != ~0ull) {  // some lane takes the trig branch
            const float p3s = (fabsf(p3) > 1e-9f) ? p3 : 1e-9f;
            const float aarg = -sqrtf(fmaxf(-27.0f / p3s, 0.0f)) * q * 0.5f;
            const float v = acosf(fminf(fmaxf(aarg, -1.0f), 1.0f)) / 3.0f;
            const float m = cosf(v);
            const float nn = sinf(v) * 1.7320508075688772f;
            const float sp = sqrtf(fmaxf(-p_ / 3.0f, 0.0f));
            const float r1 = (m + m) * sp - ca3;
            const float r2 = (-nn - m) * sp - ca3;
            if (!sgl) { T0 = r1; T1 = r2; }
        }
        T0 = fminf(fmaxf(T0, 0.0f), 1.0f);
        T1 = fminf(fmaxf(T1, 0.0f), 1.0f);

        const float Dy = Ay + Ay, Dx = Ax + Ax;
        const float d1y = (Dy + By*T0)*T0 - Cy, d1x = (Dx + Bx*T0)*T0 - Cx;
        const float q1 = d1y*d1y + d1x*d1x;
        float dist;
        if (bd == ~0ull) {
            dist = sqrtf(q1);            // T1==T0 -> q2==q1 bitwise
        } else {
            const float d2y = (Dy + By*T1)*T1 - Cy, d2x = (Dx + Bx*T1)*T1 - Cx;
            const float q2 = d2y*d2y + d2x*d2x;
            dist = sqrtf(fminf(q1, q2));
        }

        const float sarg = (w - dist) / w * 6.0f;
        sum += s_lc[n] / (1.0f + expf(-sarg));
    }

    out[py_i * 512 + px_i] = 1.0f - sum;
}

extern "C" void kernel_launch(void* const* d_in, const int* in_sizes, int n_in,
                              void* d_out, int out_size, void* d_ws, size_t ws_size,
                              hipStream_t stream) {
    const float* a  = (const float*)d_in[0];
    const float* b  = (const float*)d_in[1];
    const float* c  = (const float*)d_in[2];
    const float* lw = (const float*)d_in[3];
    const float* lc = (const float*)d_in[4];
    float* out = (float*)d_out;
    spline_render<<<dim3(1024), dim3(256), 0, stream>>>(a, b, c, lw, lc, out);
}